// Round 28
// baseline (83.370 us; speedup 1.0000x reference)
//
#include <hip/hip_runtime.h>
#include <float.h>

#define L_TOK 65536
#define DIM   64
#define NCODE 1024
#define KCAP  8

typedef __attribute__((ext_vector_type(8))) short bf16x8;
typedef __attribute__((ext_vector_type(4))) float f32x4;

__device__ __forceinline__ unsigned short f2bf(float f) {
    unsigned u = __float_as_uint(f);
    u += 0x7FFF + ((u >> 16) & 1);          // RNE to bf16 (no NaN inputs)
    return (unsigned short)(u >> 16);
}
__device__ __forceinline__ unsigned f2ord(float f) {   // order-preserving uint
    unsigned u = __float_as_uint(f);
    return (u & 0x80000000u) ? ~u : (u | 0x80000000u);
}
__device__ __forceinline__ float ord2f(unsigned o) {   // exact inverse
    unsigned u = (o & 0x80000000u) ? (o & 0x7FFFFFFFu) : ~o;
    return __uint_as_float(u);
}

// ---------------------------------------------------------------------------
// Kernel S0: fused setup = init(key,thr_ord) + esum/eb (blocks 0-3) + prep
// (r27-proven verbatim).
// ---------------------------------------------------------------------------
__global__ __launch_bounds__(256) void setup_kernel(const float* __restrict__ z,
                                                    const float* __restrict__ emb,
                                                    float* __restrict__ esum,
                                                    unsigned short* __restrict__ eb,
                                                    float* __restrict__ zs_out,
                                                    float* __restrict__ marg_out,
                                                    unsigned long long* __restrict__ key,
                                                    unsigned* __restrict__ thr_ord) {
    __shared__ float zl[256][65];
    const int t  = threadIdx.x;
    const int b  = blockIdx.x;
    const int i  = b * 256 + t;

    key[i]     = ~0ull;
    thr_ord[i] = ~0u;

    if (b < 4) {
        const int n = i;                     // code index 0..1023
        const float* e = emb + ((size_t)n << 6);
        float s = 0.f;
#pragma unroll
        for (int k = 0; k < DIM; ++k) s = fmaf(e[k], e[k], s);
        esum[n] = s;
#pragma unroll
        for (int k = 0; k < DIM; ++k) eb[(n << 6) + k] = f2bf(e[k]);
    }

    const int bb = b * 256;
    for (int j = t; j < 4096; j += 256) {
        float4 v = ((const float4*)(z + ((size_t)bb << 6)))[j];
        int tok = j >> 4, k = (j & 15) * 4;
        zl[tok][k] = v.x; zl[tok][k+1] = v.y; zl[tok][k+2] = v.z; zl[tok][k+3] = v.w;
    }
    __syncthreads();
    float zs = 0.f, sa = 0.f;
#pragma unroll
    for (int k = 0; k < DIM; ++k) {
        float v = zl[t][k];
        zs = fmaf(v, v, zs);                // EXACT reference chain order
        sa += fabsf(v);
    }
    zs_out[bb + t]   = zs;
    marg_out[bb + t] = fmaf(sa, 2.4e-5f, 6e-5f);
}

// ---------------------------------------------------------------------------
// Screen1 (min pass): r23/r26 compute body VERBATIM; minw[8][128] (4 KB)
// replaced by minord[128] (0.5 KB) reduced via LDS atomicMin on f2ord(v)
// (order-isomorphic, min is order-independent -> identical threshold bits).
// LDS 20.5 -> 16.5 KB so 4 blocks/CU = 66 KB is safely concurrent-resident
// (r14: usable concurrent LDS in [80,96) KB).
// ---------------------------------------------------------------------------
__global__ __launch_bounds__(512, 2) void screen1_kernel(const float* __restrict__ z,
                                                         const unsigned short* __restrict__ eb,
                                                         const float* __restrict__ esum,
                                                         unsigned* __restrict__ thr_ord) {
    __shared__ unsigned short zbf[128 * 64];   // swizzled bf16 [tok][k], 16 KB
    __shared__ unsigned minord[128];           // 0.5 KB

    const int t    = threadIdx.x;
    const int lane = t & 63;
    const int w    = __builtin_amdgcn_readfirstlane(t >> 6);
    const int bb   = (blockIdx.x >> 1) * 128;
    const int ch   = blockIdx.x & 1;
    char* zb = (char*)zbf;

    {   // stage z -> bf16 LDS, swizzled (r18-r27 verbatim)
        const int row = t >> 2, q = t & 3;
        const int sw  = (row & 7) << 4;
        const float* zr = z + ((size_t)(bb + row) << 6) + q * 16;
        bf16x8 c0, c1;
#pragma unroll
        for (int i = 0; i < 8; ++i) { c0[i] = (short)f2bf(zr[i]); c1[i] = (short)f2bf(zr[i + 8]); }
        *(bf16x8*)(zb + row * 128 + ((q * 32) ^ sw))      = c0;
        *(bf16x8*)(zb + row * 128 + ((q * 32 + 16) ^ sw)) = c1;
    }
    if (t < 128) minord[t] = ~0u;

    const int r16 = lane & 15;
    const int kg  = lane >> 4;

    bf16x8 bq[4][2];
    float  esv[4];
#pragma unroll
    for (int ct = 0; ct < 4; ++ct) {
        const int code = ch * 512 + w * 64 + ct * 16 + r16;
        bq[ct][0] = *(const bf16x8*)(eb + ((size_t)code << 6) + kg * 8);
        bq[ct][1] = *(const bf16x8*)(eb + ((size_t)code << 6) + 32 + kg * 8);
        esv[ct]   = esum[code];
    }
    __syncthreads();

#pragma unroll
    for (int tile = 0; tile < 8; ++tile) {
        const int arow = tile * 16 + r16;
        const int asw  = (arow & 7) << 4;
        bf16x8 af0 = *(const bf16x8*)(zb + arow * 128 + ((kg * 16) ^ asw));
        bf16x8 af1 = *(const bf16x8*)(zb + arow * 128 + ((64 + kg * 16) ^ asw));
        f32x4 mnq = {FLT_MAX, FLT_MAX, FLT_MAX, FLT_MAX};
#pragma unroll
        for (int ct = 0; ct < 4; ++ct) {
            f32x4 acc = {0.f, 0.f, 0.f, 0.f};
            acc = __builtin_amdgcn_mfma_f32_16x16x32_bf16(af0, bq[ct][0], acc, 0, 0, 0);
            acc = __builtin_amdgcn_mfma_f32_16x16x32_bf16(af1, bq[ct][1], acc, 0, 0, 0);
#pragma unroll
            for (int r = 0; r < 4; ++r) {
                float q = fmaf(acc[r], -2.0f, esv[ct]);
                mnq[r] = fminf(mnq[r], q);
            }
        }
#pragma unroll
        for (int r = 0; r < 4; ++r) {
            float v = mnq[r];
            v = fminf(v, __shfl_xor(v, 1));
            v = fminf(v, __shfl_xor(v, 2));
            v = fminf(v, __shfl_xor(v, 4));
            v = fminf(v, __shfl_xor(v, 8));
            if (r16 == 0) atomicMin(&minord[tile * 16 + kg * 4 + r], f2ord(v));
        }
    }
    __syncthreads();
    if (t < 128) atomicMin(&thr_ord[bb + t], minord[t]);
}

// ---------------------------------------------------------------------------
// Screen2R: ballot + fused exact recheck (r23/r26 compute bodies VERBATIM).
// LDS trims: bestk[4][128] (4 KB) removed -- each slot atomicMins its key
// directly to global (same key set, min order-independent -> same result);
// cand_l KCAP 16 -> 8 (P(overflow per half) ~ 1e-8; fallback = proven exact
// half-scan). LDS 25.6 -> 19 KB so 4 blocks/CU = 76 KB < 80 resident.
// ---------------------------------------------------------------------------
__global__ __launch_bounds__(512, 2) void screen2r_kernel(const float* __restrict__ z,
                                                          const unsigned short* __restrict__ eb,
                                                          const float* __restrict__ esum,
                                                          const float* __restrict__ zs_g,
                                                          const float* __restrict__ marg,
                                                          const unsigned* __restrict__ thr_ord,
                                                          const float* __restrict__ emb,
                                                          unsigned long long* __restrict__ key) {
    __shared__ unsigned short zbf[128 * 64];       // 16 KB
    __shared__ float thr_l[128];                   // 0.5 KB
    __shared__ int   cnt_l[128];                   // 0.5 KB
    __shared__ unsigned short cand_l[128 * KCAP];  // 2 KB

    const int t    = threadIdx.x;
    const int lane = t & 63;
    const int w    = __builtin_amdgcn_readfirstlane(t >> 6);
    const int bb   = (blockIdx.x >> 1) * 128;
    const int ch   = blockIdx.x & 1;
    char* zb = (char*)zbf;

    {   // stage z -> bf16 LDS, swizzled (identical bits to screen1)
        const int row = t >> 2, q = t & 3;
        const int sw  = (row & 7) << 4;
        const float* zr = z + ((size_t)(bb + row) << 6) + q * 16;
        bf16x8 c0, c1;
#pragma unroll
        for (int i = 0; i < 8; ++i) { c0[i] = (short)f2bf(zr[i]); c1[i] = (short)f2bf(zr[i + 8]); }
        *(bf16x8*)(zb + row * 128 + ((q * 32) ^ sw))      = c0;
        *(bf16x8*)(zb + row * 128 + ((q * 32 + 16) ^ sw)) = c1;
    }
    if (t < 128) {
        thr_l[t] = ord2f(thr_ord[bb + t]) + marg[bb + t];
        cnt_l[t] = 0;
    }

    const int r16 = lane & 15;
    const int kg  = lane >> 4;

    bf16x8 bq[4][2];
    float  esv[4];
#pragma unroll
    for (int ct = 0; ct < 4; ++ct) {
        const int code = ch * 512 + w * 64 + ct * 16 + r16;
        bq[ct][0] = *(const bf16x8*)(eb + ((size_t)code << 6) + kg * 8);
        bq[ct][1] = *(const bf16x8*)(eb + ((size_t)code << 6) + 32 + kg * 8);
        esv[ct]   = esum[code];
    }
    __syncthreads();

#pragma unroll
    for (int tile = 0; tile < 8; ++tile) {
        const int arow = tile * 16 + r16;
        const int asw  = (arow & 7) << 4;
        bf16x8 af0 = *(const bf16x8*)(zb + arow * 128 + ((kg * 16) ^ asw));
        bf16x8 af1 = *(const bf16x8*)(zb + arow * 128 + ((64 + kg * 16) ^ asw));
        float thrv[4];
#pragma unroll
        for (int r = 0; r < 4; ++r) thrv[r] = thr_l[tile * 16 + kg * 4 + r];
#pragma unroll
        for (int ct = 0; ct < 4; ++ct) {
            f32x4 acc = {0.f, 0.f, 0.f, 0.f};
            acc = __builtin_amdgcn_mfma_f32_16x16x32_bf16(af0, bq[ct][0], acc, 0, 0, 0);
            acc = __builtin_amdgcn_mfma_f32_16x16x32_bf16(af1, bq[ct][1], acc, 0, 0, 0);
#pragma unroll
            for (int r = 0; r < 4; ++r) {
                float q = fmaf(acc[r], -2.0f, esv[ct]);
                unsigned long long mask = __ballot(q <= thrv[r]);
                if (r16 == 0) {
                    unsigned bits = (unsigned)((mask >> (kg * 16)) & 0xFFFFull);
                    int tok = tile * 16 + kg * 4 + r;
                    while (bits) {
                        int b = __builtin_ctz(bits);
                        bits &= bits - 1;
                        int pos = atomicAdd(&cnt_l[tok], 1);
                        if (pos < KCAP)
                            cand_l[tok * KCAP + pos] =
                                (unsigned short)(ch * 512 + w * 64 + ct * 16 + b);
                    }
                }
            }
        }
    }
    __syncthreads();

    // ---- fused exact recheck (4 slots per token; direct global key merge) ----
    {
        const int tok   = t & 127;
        const int slot  = t >> 7;
        const int token = bb + tok;
        const float* zr = z + ((size_t)token << 6);
        const float  zsx = zs_g[token];
        const int    n   = cnt_l[tok];

        unsigned long long best = ~0ull;
        if (n <= KCAP) {
            for (int j = slot; j < n; j += 4) {
                int c = cand_l[tok * KCAP + j];
                const float* er = emb + ((size_t)c << 6);
                float a = 0.f;
#pragma unroll
                for (int k = 0; k < DIM; ++k) a = fmaf(zr[k], er[k], a);
                float d = fmaf(a, -2.0f, zsx + esum[c]);     // reference-bitwise
                unsigned long long kk = ((unsigned long long)f2ord(d) << 32) | (unsigned)c;
                if (kk < best) best = kk;
            }
        } else {
            for (int c = ch * 512 + slot; c < ch * 512 + 512; c += 4) {  // half fallback
                const float* er = emb + ((size_t)c << 6);
                float a = 0.f;
#pragma unroll
                for (int k = 0; k < DIM; ++k) a = fmaf(zr[k], er[k], a);
                float d = fmaf(a, -2.0f, zsx + esum[c]);
                unsigned long long kk = ((unsigned long long)f2ord(d) << 32) | (unsigned)c;
                if (kk < best) best = kk;
            }
        }
        if (best != ~0ull) atomicMin(&key[token], best);
    }
}

// ---------------------------------------------------------------------------
// Kernel C: z_q_st + f64 loss partials + idx extraction (r25-r27-proven).
// ---------------------------------------------------------------------------
__global__ __launch_bounds__(256) void output_kernel(const float* __restrict__ z,
                                                     const float* __restrict__ emb,
                                                     const unsigned long long* __restrict__ key,
                                                     float* __restrict__ idx_out,
                                                     float* __restrict__ zq_out,
                                                     double* __restrict__ partials) {
    __shared__ double wsum[4];
    const int gid  = blockIdx.x * 256 + threadIdx.x;
    const int base = gid * 4;
    const int l    = base >> 6;
    const int k0   = base & 63;
    const int idx  = (int)(unsigned)(key[l] & 0xFFFFFFFFull);

    float4 zv = *(const float4*)(z + base);
    float4 ev = *(const float4*)(emb + (idx << 6) + k0);
    float tx = ev.x - zv.x, ty = ev.y - zv.y, tz = ev.z - zv.z, tw = ev.w - zv.w;
    float4 o;
    o.x = zv.x + tx; o.y = zv.y + ty; o.z = zv.z + tz; o.w = zv.w + tw;
    *(float4*)(zq_out + base) = o;
    if (k0 == 0) idx_out[l] = (float)idx;

    double s = (double)(tx * tx);
    s += (double)(ty * ty);
    s += (double)(tz * tz);
    s += (double)(tw * tw);

#pragma unroll
    for (int off = 32; off > 0; off >>= 1) s += __shfl_down(s, off);
    if ((threadIdx.x & 63) == 0) wsum[threadIdx.x >> 6] = s;
    __syncthreads();
    if (threadIdx.x == 0)
        partials[blockIdx.x] = wsum[0] + wsum[1] + wsum[2] + wsum[3];
}

// ---------------------------------------------------------------------------
// Kernel D: final deterministic reduction (4096 partials, fixed order).
// ---------------------------------------------------------------------------
__global__ __launch_bounds__(256) void loss_kernel(const double* __restrict__ partials,
                                                   float* __restrict__ loss_out) {
    __shared__ double red[256];
    int t = threadIdx.x;
    double s = 0.0;
    for (int i = 0; i < 16; ++i) s += partials[t * 16 + i];
    red[t] = s;
    __syncthreads();
    for (int st = 128; st > 0; st >>= 1) {
        if (t < st) red[t] += red[t + st];
        __syncthreads();
    }
    if (t == 0) {
        double m  = red[0] / (double)(L_TOK * DIM);
        float  mf = (float)m;
        loss_out[0] = 0.25f * mf + mf;
    }
}

extern "C" void kernel_launch(void* const* d_in, const int* in_sizes, int n_in,
                              void* d_out, int out_size, void* d_ws, size_t ws_size,
                              hipStream_t stream) {
    const float* z   = (const float*)d_in[0];
    const float* emb = (const float*)d_in[1];

    float* out   = (float*)d_out;
    float* zq    = out;                 // [0, 4194304)
    float* loss  = out + 4194304;       // [4194304]
    float* idxf  = out + 4194305;       // [4194305, 4259841)

    char* ws = (char*)d_ws;
    float*              esum     = (float*)ws;                          // @0       4 KB
    unsigned short*     eb       = (unsigned short*)(ws + 8192);        // @8K    128 KB
    float*              zs       = (float*)(ws + 139264);               // @136K  256 KB
    float*              marg     = (float*)(ws + 401408);               // @392K  256 KB
    double*             partials = (double*)(ws + 663552);              // @648K   32 KB
    unsigned long long* key      = (unsigned long long*)(ws + 696320);  // @680K  512 KB
    unsigned*           thr_ord  = (unsigned*)(ws + 1220608);           // @1192K 256 KB

    setup_kernel   <<<256,  256, 0, stream>>>(z, emb, esum, eb, zs, marg, key, thr_ord);
    screen1_kernel <<<1024, 512, 0, stream>>>(z, eb, esum, thr_ord);
    screen2r_kernel<<<1024, 512, 0, stream>>>(z, eb, esum, zs, marg, thr_ord, emb, key);
    output_kernel  <<<4096, 256, 0, stream>>>(z, emb, key, idxf, zq, partials);
    loss_kernel    <<<1,    256, 0, stream>>>(partials, loss);
}

// Round 29
// 81.289 us; speedup vs baseline: 1.0256x; 1.0256x over previous
//
#include <hip/hip_runtime.h>
#include <float.h>

#define L_TOK 65536
#define DIM   64
#define NCODE 1024
#define KCAP  16

typedef __attribute__((ext_vector_type(8))) short bf16x8;
typedef __attribute__((ext_vector_type(4))) float f32x4;

__device__ __forceinline__ unsigned short f2bf(float f) {
    unsigned u = __float_as_uint(f);
    u += 0x7FFF + ((u >> 16) & 1);          // RNE to bf16 (no NaN inputs)
    return (unsigned short)(u >> 16);
}
__device__ __forceinline__ unsigned f2ord(float f) {   // order-preserving uint
    unsigned u = __float_as_uint(f);
    return (u & 0x80000000u) ? ~u : (u | 0x80000000u);
}
__device__ __forceinline__ float ord2f(unsigned o) {   // exact inverse
    unsigned u = (o & 0x80000000u) ? (o & 0x7FFFFFFFu) : ~o;
    return __uint_as_float(u);
}

// ---------------------------------------------------------------------------
// Kernel S0: fused setup = init(key,thr_ord) + esum/eb (blocks 0-3) + prep.
// (r27-proven, 81.4us configuration, verbatim)
// ---------------------------------------------------------------------------
__global__ __launch_bounds__(256) void setup_kernel(const float* __restrict__ z,
                                                    const float* __restrict__ emb,
                                                    float* __restrict__ esum,
                                                    unsigned short* __restrict__ eb,
                                                    float* __restrict__ zs_out,
                                                    float* __restrict__ marg_out,
                                                    unsigned long long* __restrict__ key,
                                                    unsigned* __restrict__ thr_ord) {
    __shared__ float zl[256][65];
    const int t  = threadIdx.x;
    const int b  = blockIdx.x;
    const int i  = b * 256 + t;

    key[i]     = ~0ull;
    thr_ord[i] = ~0u;

    if (b < 4) {
        const int n = i;                     // code index 0..1023
        const float* e = emb + ((size_t)n << 6);
        float s = 0.f;
#pragma unroll
        for (int k = 0; k < DIM; ++k) s = fmaf(e[k], e[k], s);
        esum[n] = s;
#pragma unroll
        for (int k = 0; k < DIM; ++k) eb[(n << 6) + k] = f2bf(e[k]);
    }

    const int bb = b * 256;
    for (int j = t; j < 4096; j += 256) {
        float4 v = ((const float4*)(z + ((size_t)bb << 6)))[j];
        int tok = j >> 4, k = (j & 15) * 4;
        zl[tok][k] = v.x; zl[tok][k+1] = v.y; zl[tok][k+2] = v.z; zl[tok][k+3] = v.w;
    }
    __syncthreads();
    float zs = 0.f, sa = 0.f;
#pragma unroll
    for (int k = 0; k < DIM; ++k) {
        float v = zl[t][k];
        zs = fmaf(v, v, zs);                // EXACT reference chain order
        sa += fabsf(v);
    }
    zs_out[bb + t]   = zs;
    marg_out[bb + t] = fmaf(sa, 2.4e-5f, 6e-5f);
}

// ---------------------------------------------------------------------------
// Screen1 (min pass): r23/r26/r27 VERBATIM. Full 1024-code min. block =
// 128 tokens x code-half; wave owns 64 codes (bq[4][2] = 32 VGPR).
// ---------------------------------------------------------------------------
__global__ __launch_bounds__(512, 2) void screen1_kernel(const float* __restrict__ z,
                                                         const unsigned short* __restrict__ eb,
                                                         const float* __restrict__ esum,
                                                         unsigned* __restrict__ thr_ord) {
    __shared__ unsigned short zbf[128 * 64];   // swizzled bf16 [tok][k], 16 KB
    __shared__ float minw[8][128];             // 4 KB

    const int t    = threadIdx.x;
    const int lane = t & 63;
    const int w    = __builtin_amdgcn_readfirstlane(t >> 6);
    const int bb   = (blockIdx.x >> 1) * 128;
    const int ch   = blockIdx.x & 1;
    char* zb = (char*)zbf;

    {   // stage z -> bf16 LDS, swizzled
        const int row = t >> 2, q = t & 3;
        const int sw  = (row & 7) << 4;
        const float* zr = z + ((size_t)(bb + row) << 6) + q * 16;
        bf16x8 c0, c1;
#pragma unroll
        for (int i = 0; i < 8; ++i) { c0[i] = (short)f2bf(zr[i]); c1[i] = (short)f2bf(zr[i + 8]); }
        *(bf16x8*)(zb + row * 128 + ((q * 32) ^ sw))      = c0;
        *(bf16x8*)(zb + row * 128 + ((q * 32 + 16) ^ sw)) = c1;
    }

    const int r16 = lane & 15;
    const int kg  = lane >> 4;

    bf16x8 bq[4][2];
    float  esv[4];
#pragma unroll
    for (int ct = 0; ct < 4; ++ct) {
        const int code = ch * 512 + w * 64 + ct * 16 + r16;
        bq[ct][0] = *(const bf16x8*)(eb + ((size_t)code << 6) + kg * 8);
        bq[ct][1] = *(const bf16x8*)(eb + ((size_t)code << 6) + 32 + kg * 8);
        esv[ct]   = esum[code];
    }
    __syncthreads();

#pragma unroll
    for (int tile = 0; tile < 8; ++tile) {
        const int arow = tile * 16 + r16;
        const int asw  = (arow & 7) << 4;
        bf16x8 af0 = *(const bf16x8*)(zb + arow * 128 + ((kg * 16) ^ asw));
        bf16x8 af1 = *(const bf16x8*)(zb + arow * 128 + ((64 + kg * 16) ^ asw));
        f32x4 mnq = {FLT_MAX, FLT_MAX, FLT_MAX, FLT_MAX};
#pragma unroll
        for (int ct = 0; ct < 4; ++ct) {
            f32x4 acc = {0.f, 0.f, 0.f, 0.f};
            acc = __builtin_amdgcn_mfma_f32_16x16x32_bf16(af0, bq[ct][0], acc, 0, 0, 0);
            acc = __builtin_amdgcn_mfma_f32_16x16x32_bf16(af1, bq[ct][1], acc, 0, 0, 0);
#pragma unroll
            for (int r = 0; r < 4; ++r) {
                float q = fmaf(acc[r], -2.0f, esv[ct]);
                mnq[r] = fminf(mnq[r], q);
            }
        }
#pragma unroll
        for (int r = 0; r < 4; ++r) {
            float v = mnq[r];
            v = fminf(v, __shfl_xor(v, 1));
            v = fminf(v, __shfl_xor(v, 2));
            v = fminf(v, __shfl_xor(v, 4));
            v = fminf(v, __shfl_xor(v, 8));
            if (r16 == 0) minw[w][tile * 16 + kg * 4 + r] = v;
        }
    }
    __syncthreads();
    if (t < 128) {
        float m = minw[0][t];
#pragma unroll
        for (int ww = 1; ww < 8; ++ww) m = fminf(m, minw[ww][t]);
        atomicMin(&thr_ord[bb + t], f2ord(m));
    }
}

// ---------------------------------------------------------------------------
// Screen2R: ballot + fused exact recheck (r23/r26/r27 VERBATIM, KCAP=16).
// ---------------------------------------------------------------------------
__global__ __launch_bounds__(512, 2) void screen2r_kernel(const float* __restrict__ z,
                                                          const unsigned short* __restrict__ eb,
                                                          const float* __restrict__ esum,
                                                          const float* __restrict__ zs_g,
                                                          const float* __restrict__ marg,
                                                          const unsigned* __restrict__ thr_ord,
                                                          const float* __restrict__ emb,
                                                          unsigned long long* __restrict__ key) {
    __shared__ unsigned short zbf[128 * 64];       // 16 KB
    __shared__ float thr_l[128];                   // 0.5 KB
    __shared__ int   cnt_l[128];                   // 0.5 KB
    __shared__ unsigned short cand_l[128 * KCAP];  // 4 KB
    __shared__ unsigned long long bestk[4][128];   // 4 KB

    const int t    = threadIdx.x;
    const int lane = t & 63;
    const int w    = __builtin_amdgcn_readfirstlane(t >> 6);
    const int bb   = (blockIdx.x >> 1) * 128;
    const int ch   = blockIdx.x & 1;
    char* zb = (char*)zbf;

    {   // stage z -> bf16 LDS, swizzled (identical bits to screen1)
        const int row = t >> 2, q = t & 3;
        const int sw  = (row & 7) << 4;
        const float* zr = z + ((size_t)(bb + row) << 6) + q * 16;
        bf16x8 c0, c1;
#pragma unroll
        for (int i = 0; i < 8; ++i) { c0[i] = (short)f2bf(zr[i]); c1[i] = (short)f2bf(zr[i + 8]); }
        *(bf16x8*)(zb + row * 128 + ((q * 32) ^ sw))      = c0;
        *(bf16x8*)(zb + row * 128 + ((q * 32 + 16) ^ sw)) = c1;
    }
    if (t < 128) {
        thr_l[t] = ord2f(thr_ord[bb + t]) + marg[bb + t];
        cnt_l[t] = 0;
    }

    const int r16 = lane & 15;
    const int kg  = lane >> 4;

    bf16x8 bq[4][2];
    float  esv[4];
#pragma unroll
    for (int ct = 0; ct < 4; ++ct) {
        const int code = ch * 512 + w * 64 + ct * 16 + r16;
        bq[ct][0] = *(const bf16x8*)(eb + ((size_t)code << 6) + kg * 8);
        bq[ct][1] = *(const bf16x8*)(eb + ((size_t)code << 6) + 32 + kg * 8);
        esv[ct]   = esum[code];
    }
    __syncthreads();

#pragma unroll
    for (int tile = 0; tile < 8; ++tile) {
        const int arow = tile * 16 + r16;
        const int asw  = (arow & 7) << 4;
        bf16x8 af0 = *(const bf16x8*)(zb + arow * 128 + ((kg * 16) ^ asw));
        bf16x8 af1 = *(const bf16x8*)(zb + arow * 128 + ((64 + kg * 16) ^ asw));
        float thrv[4];
#pragma unroll
        for (int r = 0; r < 4; ++r) thrv[r] = thr_l[tile * 16 + kg * 4 + r];
#pragma unroll
        for (int ct = 0; ct < 4; ++ct) {
            f32x4 acc = {0.f, 0.f, 0.f, 0.f};
            acc = __builtin_amdgcn_mfma_f32_16x16x32_bf16(af0, bq[ct][0], acc, 0, 0, 0);
            acc = __builtin_amdgcn_mfma_f32_16x16x32_bf16(af1, bq[ct][1], acc, 0, 0, 0);
#pragma unroll
            for (int r = 0; r < 4; ++r) {
                float q = fmaf(acc[r], -2.0f, esv[ct]);
                unsigned long long mask = __ballot(q <= thrv[r]);
                if (r16 == 0) {
                    unsigned bits = (unsigned)((mask >> (kg * 16)) & 0xFFFFull);
                    int tok = tile * 16 + kg * 4 + r;
                    while (bits) {
                        int b = __builtin_ctz(bits);
                        bits &= bits - 1;
                        int pos = atomicAdd(&cnt_l[tok], 1);
                        if (pos < KCAP)
                            cand_l[tok * KCAP + pos] =
                                (unsigned short)(ch * 512 + w * 64 + ct * 16 + b);
                    }
                }
            }
        }
    }
    __syncthreads();

    // ---- fused exact recheck (4 slots per token, this half's candidates) ----
    {
        const int tok   = t & 127;
        const int slot  = t >> 7;
        const int token = bb + tok;
        const float* zr = z + ((size_t)token << 6);
        const float  zsx = zs_g[token];
        const int    n   = cnt_l[tok];

        unsigned long long best = ~0ull;
        if (n <= KCAP) {
            for (int j = slot; j < n; j += 4) {
                int c = cand_l[tok * KCAP + j];
                const float* er = emb + ((size_t)c << 6);
                float a = 0.f;
#pragma unroll
                for (int k = 0; k < DIM; ++k) a = fmaf(zr[k], er[k], a);
                float d = fmaf(a, -2.0f, zsx + esum[c]);     // reference-bitwise
                unsigned long long kk = ((unsigned long long)f2ord(d) << 32) | (unsigned)c;
                if (kk < best) best = kk;
            }
        } else {
            for (int c = ch * 512 + slot; c < ch * 512 + 512; c += 4) {  // half fallback
                const float* er = emb + ((size_t)c << 6);
                float a = 0.f;
#pragma unroll
                for (int k = 0; k < DIM; ++k) a = fmaf(zr[k], er[k], a);
                float d = fmaf(a, -2.0f, zsx + esum[c]);
                unsigned long long kk = ((unsigned long long)f2ord(d) << 32) | (unsigned)c;
                if (kk < best) best = kk;
            }
        }
        bestk[slot][tok] = best;
    }
    __syncthreads();
    if (t < 128) {
        unsigned long long b = bestk[0][t];
        if (bestk[1][t] < b) b = bestk[1][t];
        if (bestk[2][t] < b) b = bestk[2][t];
        if (bestk[3][t] < b) b = bestk[3][t];
        if (b != ~0ull) atomicMin(&key[bb + t], b);
    }
}

// ---------------------------------------------------------------------------
// Kernel C: z_q_st + f64 loss partials + idx extraction (r25-r27-proven).
// ---------------------------------------------------------------------------
__global__ __launch_bounds__(256) void output_kernel(const float* __restrict__ z,
                                                     const float* __restrict__ emb,
                                                     const unsigned long long* __restrict__ key,
                                                     float* __restrict__ idx_out,
                                                     float* __restrict__ zq_out,
                                                     double* __restrict__ partials) {
    __shared__ double wsum[4];
    const int gid  = blockIdx.x * 256 + threadIdx.x;
    const int base = gid * 4;
    const int l    = base >> 6;
    const int k0   = base & 63;
    const int idx  = (int)(unsigned)(key[l] & 0xFFFFFFFFull);

    float4 zv = *(const float4*)(z + base);
    float4 ev = *(const float4*)(emb + (idx << 6) + k0);
    float tx = ev.x - zv.x, ty = ev.y - zv.y, tz = ev.z - zv.z, tw = ev.w - zv.w;
    float4 o;
    o.x = zv.x + tx; o.y = zv.y + ty; o.z = zv.z + tz; o.w = zv.w + tw;
    *(float4*)(zq_out + base) = o;
    if (k0 == 0) idx_out[l] = (float)idx;

    double s = (double)(tx * tx);
    s += (double)(ty * ty);
    s += (double)(tz * tz);
    s += (double)(tw * tw);

#pragma unroll
    for (int off = 32; off > 0; off >>= 1) s += __shfl_down(s, off);
    if ((threadIdx.x & 63) == 0) wsum[threadIdx.x >> 6] = s;
    __syncthreads();
    if (threadIdx.x == 0)
        partials[blockIdx.x] = wsum[0] + wsum[1] + wsum[2] + wsum[3];
}

// ---------------------------------------------------------------------------
// Kernel D: final deterministic reduction (4096 partials, fixed order).
// ---------------------------------------------------------------------------
__global__ __launch_bounds__(256) void loss_kernel(const double* __restrict__ partials,
                                                   float* __restrict__ loss_out) {
    __shared__ double red[256];
    int t = threadIdx.x;
    double s = 0.0;
    for (int i = 0; i < 16; ++i) s += partials[t * 16 + i];
    red[t] = s;
    __syncthreads();
    for (int st = 128; st > 0; st >>= 1) {
        if (t < st) red[t] += red[t + st];
        __syncthreads();
    }
    if (t == 0) {
        double m  = red[0] / (double)(L_TOK * DIM);
        float  mf = (float)m;
        loss_out[0] = 0.25f * mf + mf;
    }
}

extern "C" void kernel_launch(void* const* d_in, const int* in_sizes, int n_in,
                              void* d_out, int out_size, void* d_ws, size_t ws_size,
                              hipStream_t stream) {
    const float* z   = (const float*)d_in[0];
    const float* emb = (const float*)d_in[1];

    float* out   = (float*)d_out;
    float* zq    = out;                 // [0, 4194304)
    float* loss  = out + 4194304;       // [4194304]
    float* idxf  = out + 4194305;       // [4194305, 4259841)

    char* ws = (char*)d_ws;
    float*              esum     = (float*)ws;                          // @0       4 KB
    unsigned short*     eb       = (unsigned short*)(ws + 8192);        // @8K    128 KB
    float*              zs       = (float*)(ws + 139264);               // @136K  256 KB
    float*              marg     = (float*)(ws + 401408);               // @392K  256 KB
    double*             partials = (double*)(ws + 663552);              // @648K   32 KB
    unsigned long long* key      = (unsigned long long*)(ws + 696320);  // @680K  512 KB
    unsigned*           thr_ord  = (unsigned*)(ws + 1220608);           // @1192K 256 KB

    setup_kernel   <<<256,  256, 0, stream>>>(z, emb, esum, eb, zs, marg, key, thr_ord);
    screen1_kernel <<<1024, 512, 0, stream>>>(z, eb, esum, thr_ord);
    screen2r_kernel<<<1024, 512, 0, stream>>>(z, eb, esum, zs, marg, thr_ord, emb, key);
    output_kernel  <<<4096, 256, 0, stream>>>(z, emb, key, idxf, zq, partials);
    loss_kernel    <<<1,    256, 0, stream>>>(partials, loss);
}